// Round 6
// baseline (508.571 us; speedup 1.0000x reference)
//
#include <hip/hip_runtime.h>
#include <hip/hip_bf16.h>

constexpr int NN   = 10000;   // nodes
constexpr int INF  = 50;      // in feats
constexpr int HID  = 512;     // hidden
constexpr int OUTF = 121;     // out feats
constexpr int NE   = 160000;  // edges
constexpr int DMAX = 64;      // per-node neighbor capacity (Poisson(16): P(deg>64) ~ 1e-19)

typedef __attribute__((ext_vector_type(8))) short short8;
typedef __attribute__((ext_vector_type(4))) float floatx4;

__device__ inline float bf2f(unsigned short u) {
    union { unsigned int i; float f; } v; v.i = ((unsigned)u) << 16; return v.f;
}
__device__ inline unsigned short f2bf(float f) {
    __hip_bfloat16 h = __float2bfloat16(f);
    return *(unsigned short*)&h;
}

// ======== DIAGNOSTIC ROUND: every kernel repeats its (idempotent) work `reps` times ========
// so per-kernel durations clear the 43us harness-fill bar and appear in the top-5 profile.

// ---------------- prep: zero cursor + pack weights (MFMA B-frag order) + pack xp ----------------

__global__ __launch_bounds__(256) void k_prep(const float* __restrict__ x,
                                              const float* __restrict__ W1l, const float* __restrict__ W1r,
                                              const float* __restrict__ W2l, const float* __restrict__ W2r,
                                              int* __restrict__ cursor, __hip_bfloat16* __restrict__ xp,
                                              __hip_bfloat16* __restrict__ B1p, __hip_bfloat16* __restrict__ B2p,
                                              int reps) {
    int idx = blockIdx.x * 256 + threadIdx.x;
    for (int rep = 0; rep < reps; ++rep) {
        if (idx < NN) cursor[idx] = 0;
        if (idx < 65536) {  // B1p: W1cat[128x512] = vstack(W1l[50], W1r[50], 0[28]); KT=4, NT=32
            int j = idx & 7, L = (idx >> 3) & 63, kt = (idx >> 9) & 3, nt = idx >> 11;
            int k = kt * 32 + ((L >> 4) * 8 + j);
            int n = nt * 16 + (L & 15);
            float v = (k < 50) ? W1l[k * HID + n] : ((k < 100) ? W1r[(k - 50) * HID + n] : 0.f);
            B1p[idx] = __float2bfloat16(v);
        }
        {   // B2p: W2cat[512x256] = [pad128(W2l) | pad128(W2r)]; KT=16, NT=16
            int j = idx & 7, L = (idx >> 3) & 63, kt = (idx >> 9) & 15, nt = idx >> 13;
            int k = kt * 32 + ((L >> 4) * 8 + j);
            int n = nt * 16 + (L & 15);
            float v;
            if (n < 128) v = (n < OUTF) ? W2l[k * OUTF + n] : 0.f;
            else { int c = n - 128; v = (c < OUTF) ? W2r[k * OUTF + c] : 0.f; }
            B2p[idx] = __float2bfloat16(v);
        }
        for (int r = idx; r < NN * 64; r += 131072) {
            int n = r >> 6, c = r & 63;
            xp[r] = __float2bfloat16(c < INF ? x[n * INF + c] : 0.f);
        }
    }
}

// ---------------- fixed-capacity CSR fill; rep 0 = real, reps>0 = throwaway (same inst mix) --------

__global__ __launch_bounds__(256) void k_fill(const int* __restrict__ srcv, const int* __restrict__ dstv,
                                              int* __restrict__ cursor, int* __restrict__ csr,
                                              int* __restrict__ cursor2, int* __restrict__ csr2,
                                              int reps) {
    int e = blockIdx.x * 256 + threadIdx.x;
    for (int rep = 0; rep < reps; ++rep) {
        if (e < NE) {
            int d = dstv[e];
            if ((unsigned)d < (unsigned)NN) {
                int s = srcv[e];
                s = min(max(s, 0), NN - 1);           // guard: csr always holds valid node ids
                if (rep == 0) {
                    int pos = atomicAdd(&cursor[d], 1);
                    if ((unsigned)pos < (unsigned)DMAX) csr[d * DMAX + pos] = s;
                } else {
                    int pos = atomicAdd(&cursor2[d], 1);
                    csr2[d * DMAX + (pos & 63)] = s;  // masked: in-range, throwaway
                }
            }
        }
    }
}

// ---------------- fused agg1 + GEMM1 + GEMM2: 16 nodes per block, everything via LDS ----------------

__global__ __launch_bounds__(256) void k_fused(const __hip_bfloat16* __restrict__ xp,
                                               const int* __restrict__ cursor, const int* __restrict__ csr,
                                               const __hip_bfloat16* __restrict__ B1p,
                                               const float* __restrict__ b1,
                                               const __hip_bfloat16* __restrict__ B2p,
                                               __hip_bfloat16* __restrict__ Pb, float* __restrict__ Q,
                                               int reps) {
    __shared__ __align__(16) unsigned short As[16 * 136];
    __shared__ __align__(16) unsigned short Ht[16 * 520];
    int t = threadIdx.x;
    int w = t >> 6, lane = t & 63, quad = lane >> 4, l16 = lane & 15;
    int m0 = blockIdx.x * 16;
    const unsigned short* xs = (const unsigned short*)xp;

    for (int rep = 0; rep < reps; ++rep) {
        // ---- phase A ----
#pragma unroll
        for (int p = 0; p < 4; ++p) {
            int nl = w * 4 + p, n = m0 + nl;
            int dt = cursor[n];
            int d = min(dt, DMAX);
            int ids = csr[n * DMAX + lane];
            float s0 = 0.f, s1 = 0.f, s2 = 0.f, s3 = 0.f;
            int j = 0;
            for (; j + 4 <= d; j += 4) {
                int a = __shfl(ids, j), b = __shfl(ids, j + 1), c = __shfl(ids, j + 2), e = __shfl(ids, j + 3);
                s0 += bf2f(xs[a * 64 + lane]);
                s1 += bf2f(xs[b * 64 + lane]);
                s2 += bf2f(xs[c * 64 + lane]);
                s3 += bf2f(xs[e * 64 + lane]);
            }
            for (; j < d; ++j) {
                int a = __shfl(ids, j);
                s0 += bf2f(xs[a * 64 + lane]);
            }
            float s = (s0 + s1) + (s2 + s3);
            float invd = (dt > 0) ? 1.f / (float)dt : 1.f;
            unsigned short self = xs[n * 64 + lane];
            if (lane < INF) As[nl * 136 + lane] = f2bf(s * invd);
            As[nl * 136 + 50 + lane] = self;
            if (lane < 7) *(unsigned*)&As[nl * 136 + 114 + 2 * lane] = 0u;
        }
        __syncthreads();

        // ---- phase B: wave w covers cols w*128 .. +127 of h ----
        short8 af[4];
#pragma unroll
        for (int ks = 0; ks < 4; ++ks) af[ks] = *(const short8*)&As[l16 * 136 + ks * 32 + quad * 8];
        {
            floatx4 acc[8];
#pragma unroll
            for (int nt = 0; nt < 8; ++nt) acc[nt] = floatx4{0.f, 0.f, 0.f, 0.f};
#pragma unroll
            for (int nt = 0; nt < 8; ++nt) {
                int ntile = w * 8 + nt;
                const short* Bb = (const short*)B1p + (ntile * 4 * 64 + lane) * 8;
#pragma unroll
                for (int ks = 0; ks < 4; ++ks) {
                    short8 bf = *(const short8*)(Bb + ks * 512);
                    acc[nt] = __builtin_amdgcn_mfma_f32_16x16x32_bf16(af[ks], bf, acc[nt], 0, 0, 0);
                }
            }
#pragma unroll
            for (int nt = 0; nt < 8; ++nt) {
                int col = w * 128 + nt * 16 + l16;
                float bias = b1[col];
#pragma unroll
                for (int r = 0; r < 4; ++r)
                    Ht[(quad * 4 + r) * 520 + col] = f2bf(fmaxf(acc[nt][r] + bias, 0.f));
            }
        }
        __syncthreads();

        // ---- phase C: waves 0,1 -> Pb cols 0..127; waves 2,3 -> Q cols 0..127 ----
        int isQ = w >> 1;
        int halfcol = (w & 1) * 64;
        int tbase = isQ * 8 + (w & 1) * 4;
        floatx4 acc[4];
#pragma unroll
        for (int nt = 0; nt < 4; ++nt) acc[nt] = floatx4{0.f, 0.f, 0.f, 0.f};
#pragma unroll 4
        for (int ks = 0; ks < 16; ++ks) {
            short8 a2 = *(const short8*)&Ht[l16 * 520 + ks * 32 + quad * 8];
#pragma unroll
            for (int nt = 0; nt < 4; ++nt) {
                const short* Bb = (const short*)B2p + (((tbase + nt) * 16 + ks) * 64 + lane) * 8;
                short8 bf = *(const short8*)Bb;
                acc[nt] = __builtin_amdgcn_mfma_f32_16x16x32_bf16(a2, bf, acc[nt], 0, 0, 0);
            }
        }
        if (!isQ) {
#pragma unroll
            for (int nt = 0; nt < 4; ++nt)
#pragma unroll
                for (int r = 0; r < 4; ++r) {
                    int row = m0 + quad * 4 + r;
                    Pb[row * 128 + halfcol + nt * 16 + l16] = __float2bfloat16(acc[nt][r]);
                }
        } else {
#pragma unroll
            for (int nt = 0; nt < 4; ++nt)
#pragma unroll
                for (int r = 0; r < 4; ++r) {
                    int row = m0 + quad * 4 + r;
                    Q[row * 128 + halfcol + nt * 16 + l16] = acc[nt][r];
                }
        }
        __syncthreads();   // protect Ht/As against next rep's writes
    }
}

// ---------------- final: out = mean_agg(Pb)[:, :121] + Q[:, :121] + b2; one wave per node ----------------

__global__ __launch_bounds__(256) void k_final(const __hip_bfloat16* __restrict__ Pb,
                                               const float* __restrict__ Q, const float* __restrict__ b2,
                                               const int* __restrict__ cursor, const int* __restrict__ csr,
                                               float* __restrict__ out, int reps) {
    int lane = threadIdx.x & 63;
    int n = blockIdx.x * 4 + (threadIdx.x >> 6);
    for (int rep = 0; rep < reps; ++rep) {
        int dt = cursor[n];
        int d = min(dt, DMAX);
        int ids = csr[n * DMAX + lane];
        const unsigned* Pw = (const unsigned*)Pb;
        float lo0 = 0.f, lo1 = 0.f, lo2 = 0.f, lo3 = 0.f;
        float hi0 = 0.f, hi1 = 0.f, hi2 = 0.f, hi3 = 0.f;
        int j = 0;
        for (; j + 4 <= d; j += 4) {
            int a = __shfl(ids, j), b = __shfl(ids, j + 1), c = __shfl(ids, j + 2), e = __shfl(ids, j + 3);
            unsigned w0 = Pw[a * 64 + lane];
            unsigned w1 = Pw[b * 64 + lane];
            unsigned w2 = Pw[c * 64 + lane];
            unsigned w3 = Pw[e * 64 + lane];
            lo0 += __uint_as_float(w0 << 16); hi0 += __uint_as_float(w0 & 0xffff0000u);
            lo1 += __uint_as_float(w1 << 16); hi1 += __uint_as_float(w1 & 0xffff0000u);
            lo2 += __uint_as_float(w2 << 16); hi2 += __uint_as_float(w2 & 0xffff0000u);
            lo3 += __uint_as_float(w3 << 16); hi3 += __uint_as_float(w3 & 0xffff0000u);
        }
        for (; j < d; ++j) {
            int a = __shfl(ids, j);
            unsigned w0 = Pw[a * 64 + lane];
            lo0 += __uint_as_float(w0 << 16); hi0 += __uint_as_float(w0 & 0xffff0000u);
        }
        float slo = (lo0 + lo1) + (lo2 + lo3);
        float shi = (hi0 + hi1) + (hi2 + hi3);
        float invd = (dt > 0) ? 1.f / (float)dt : 1.f;
        int c0 = lane * 2, c1 = lane * 2 + 1;
        if (c0 < OUTF) out[n * OUTF + c0] = slo * invd + Q[n * 128 + c0] + b2[c0];
        if (c1 < OUTF) out[n * OUTF + c1] = shi * invd + Q[n * 128 + c1] + b2[c1];
    }
}

extern "C" void kernel_launch(void* const* d_in, const int* in_sizes, int n_in,
                              void* d_out, int out_size, void* d_ws, size_t ws_size,
                              hipStream_t stream) {
    const float* x   = (const float*)d_in[0];
    const int* edges = (const int*)d_in[1];
    const float* W1l = (const float*)d_in[2];
    const float* W1r = (const float*)d_in[3];
    const float* b1  = (const float*)d_in[4];
    const float* W2l = (const float*)d_in[5];
    const float* W2r = (const float*)d_in[6];
    const float* b2  = (const float*)d_in[7];
    float* out = (float*)d_out;

    char* ws = (char*)d_ws;
    int* cursor         = (int*)(ws + 0);                    // 40,000 B
    int* csr            = (int*)(ws + 40000);                // 2,560,000 B [NN,64]
    __hip_bfloat16* xp  = (__hip_bfloat16*)(ws + 2600000);   // 1,280,000 B [NN,64]
    __hip_bfloat16* Pb  = (__hip_bfloat16*)(ws + 3880000);   // 2,560,000 B [NN,128]
    float* Q            = (float*)(ws + 6440000);            // 5,120,000 B [NN,128]
    __hip_bfloat16* B1p = (__hip_bfloat16*)(ws + 11560000);  // 131,072 B
    __hip_bfloat16* B2p = (__hip_bfloat16*)(ws + 11691072);  // 262,144 B
    int* cursor2        = (int*)(ws + 11953216);             // 40,000 B   (diagnostic throwaway)
    int* csr2           = (int*)(ws + 11993216);             // 2,560,000 B (diagnostic throwaway)

    const int* srcv = edges;
    const int* dstv = edges + NE;
    const int REPS = 8;   // diagnostic amplification; identical, idempotent work per rep

    k_prep<<<512, 256, 0, stream>>>(x, W1l, W1r, W2l, W2r, cursor, xp, B1p, B2p, REPS);
    k_fill<<<625, 256, 0, stream>>>(srcv, dstv, cursor, csr, cursor2, csr2, REPS);
    k_fused<<<625, 256, 0, stream>>>(xp, cursor, csr, B1p, b1, B2p, Pb, Q, REPS);
    k_final<<<2500, 256, 0, stream>>>(Pb, Q, b2, cursor, csr, out, REPS);
}

// Round 7
// 115.452 us; speedup vs baseline: 4.4050x; 4.4050x over previous
//
#include <hip/hip_runtime.h>
#include <hip/hip_bf16.h>

constexpr int NN   = 10000;   // nodes
constexpr int INF  = 50;      // in feats
constexpr int HID  = 512;     // hidden
constexpr int OUTF = 121;     // out feats
constexpr int NE   = 160000;  // edges
constexpr int DMAX = 64;      // per-node neighbor capacity (Poisson(16): P(deg>64) ~ 1e-19)

typedef __attribute__((ext_vector_type(8))) short short8;
typedef __attribute__((ext_vector_type(4))) float floatx4;

__device__ inline float bf2f(unsigned short u) {
    union { unsigned int i; float f; } v; v.i = ((unsigned)u) << 16; return v.f;
}
__device__ inline unsigned short f2bf(float f) {
    __hip_bfloat16 h = __float2bfloat16(f);
    return *(unsigned short*)&h;
}

// ---------------- prep: zero cursor + pack weights (MFMA B-frag order) + pack xp ----------------
// B-frag for 16x16x32: lane L holds B[k = kt*32 + (L>>4)*8 + j][n = nt*16 + (L&15)], j=0..7.
// Bp[((nt*KT + kt)*64 + L)*8 + j]: each lane's 8 elems contiguous (16B), wave coalesced.

__global__ __launch_bounds__(256) void k_prep(const float* __restrict__ x,
                                              const float* __restrict__ W1l, const float* __restrict__ W1r,
                                              const float* __restrict__ W2l, const float* __restrict__ W2r,
                                              int* __restrict__ cursor, __hip_bfloat16* __restrict__ xp,
                                              __hip_bfloat16* __restrict__ B1p, __hip_bfloat16* __restrict__ B2p) {
    int idx = blockIdx.x * 256 + threadIdx.x;
    if (idx < NN) cursor[idx] = 0;
    if (idx < 65536) {  // B1p: W1cat[128x512] = vstack(W1l[50], W1r[50], 0[28]); KT=4, NT=32
        int j = idx & 7, L = (idx >> 3) & 63, kt = (idx >> 9) & 3, nt = idx >> 11;
        int k = kt * 32 + ((L >> 4) * 8 + j);
        int n = nt * 16 + (L & 15);
        float v = (k < 50) ? W1l[k * HID + n] : ((k < 100) ? W1r[(k - 50) * HID + n] : 0.f);
        B1p[idx] = __float2bfloat16(v);
    }
    {   // B2p: W2cat[512x256] = [pad128(W2l) | pad128(W2r)]; KT=16, NT=16
        int j = idx & 7, L = (idx >> 3) & 63, kt = (idx >> 9) & 15, nt = idx >> 13;
        int k = kt * 32 + ((L >> 4) * 8 + j);
        int n = nt * 16 + (L & 15);
        float v;
        if (n < 128) v = (n < OUTF) ? W2l[k * OUTF + n] : 0.f;
        else { int c = n - 128; v = (c < OUTF) ? W2r[k * OUTF + c] : 0.f; }
        B2p[idx] = __float2bfloat16(v);
    }
    // xp[NN][64] bf16: one-cache-line gather rows (cols >= 50 zero)
    for (int r = idx; r < NN * 64; r += 131072) {
        int n = r >> 6, c = r & 63;
        xp[r] = __float2bfloat16(c < INF ? x[n * INF + c] : 0.f);
    }
}

// ---------------- fixed-capacity CSR fill ----------------

__global__ __launch_bounds__(256) void k_fill(const int* __restrict__ srcv, const int* __restrict__ dstv,
                                              int* __restrict__ cursor, int* __restrict__ csr) {
    int e = blockIdx.x * 256 + threadIdx.x;
    if (e < NE) {
        int d = dstv[e];
        if ((unsigned)d < (unsigned)NN) {
            int pos = atomicAdd(&cursor[d], 1);
            int s = srcv[e];
            s = min(max(s, 0), NN - 1);               // guard: csr always holds valid node ids
            if (pos < DMAX) csr[d * DMAX + pos] = s;
        }
    }
}

// ---------------- fused agg1 + GEMM1 + GEMM2: 16 nodes per block, 8 waves ----------------
// Phase A: scalar-load neighbor ids (s_load_dwordx8), vector-gather xp rows; 2 nodes/wave
// Phase B: h_tile = relu(As @ W1cat + b1) -> Ht[16][520]; wave w -> cols w*64..+63
// Phase C: waves 0-3 -> Pb (bf16), waves 4-7 -> Q (fp32); 32 cols/wave

__global__ __launch_bounds__(512, 4) void k_fused(const __hip_bfloat16* __restrict__ xp,
                                                  const int* __restrict__ cursor, const int* __restrict__ csr,
                                                  const __hip_bfloat16* __restrict__ B1p,
                                                  const float* __restrict__ b1,
                                                  const __hip_bfloat16* __restrict__ B2p,
                                                  __hip_bfloat16* __restrict__ Pb, float* __restrict__ Q) {
    __shared__ __align__(16) unsigned short As[16 * 136];
    __shared__ __align__(16) unsigned short Ht[16 * 520];
    int t = threadIdx.x;
    int w = t >> 6, lane = t & 63, quad = lane >> 4, l16 = lane & 15;
    int m0 = blockIdx.x * 16;
    const unsigned short* xs = (const unsigned short*)xp;

    // ---- phase A: wave w handles nodes m0 + w*2 + {0,1}; ids via scalar loads ----
#pragma unroll
    for (int p = 0; p < 2; ++p) {
        int nl = w * 2 + p;
        int nu = __builtin_amdgcn_readfirstlane(m0 + nl);   // SGPR node id -> s_load path
        int dt = cursor[nu];
        int d = min(dt, DMAX);
        const int* crow = csr + nu * DMAX;
        float s0 = 0.f, s1 = 0.f, s2 = 0.f, s3 = 0.f;
        int j = 0;
        for (; j + 8 <= d; j += 8) {                  // ids arrive as one s_load_dwordx8
            int i0 = crow[j], i1 = crow[j + 1], i2 = crow[j + 2], i3 = crow[j + 3];
            int i4 = crow[j + 4], i5 = crow[j + 5], i6 = crow[j + 6], i7 = crow[j + 7];
            s0 += bf2f(xs[i0 * 64 + lane]);
            s1 += bf2f(xs[i1 * 64 + lane]);
            s2 += bf2f(xs[i2 * 64 + lane]);
            s3 += bf2f(xs[i3 * 64 + lane]);
            s0 += bf2f(xs[i4 * 64 + lane]);
            s1 += bf2f(xs[i5 * 64 + lane]);
            s2 += bf2f(xs[i6 * 64 + lane]);
            s3 += bf2f(xs[i7 * 64 + lane]);
        }
        for (; j < d; ++j) {
            int i0 = crow[j];
            s0 += bf2f(xs[i0 * 64 + lane]);
        }
        float s = (s0 + s1) + (s2 + s3);
        float invd = (dt > 0) ? 1.f / (float)dt : 1.f;
        unsigned short self = xs[nu * 64 + lane];
        if (lane < INF) As[nl * 136 + lane] = f2bf(s * invd);
        As[nl * 136 + 50 + lane] = self;              // cols 50..113 (100..113 zeros)
        if (lane < 7) *(unsigned*)&As[nl * 136 + 114 + 2 * lane] = 0u;  // cols 114..127
    }
    __syncthreads();

    // ---- phase B: wave w covers cols w*64 .. +63 ----
    short8 af[4];
#pragma unroll
    for (int ks = 0; ks < 4; ++ks) af[ks] = *(const short8*)&As[l16 * 136 + ks * 32 + quad * 8];
    {
        floatx4 acc[4];
#pragma unroll
        for (int nt = 0; nt < 4; ++nt) acc[nt] = floatx4{0.f, 0.f, 0.f, 0.f};
#pragma unroll
        for (int nt = 0; nt < 4; ++nt) {
            int ntile = w * 4 + nt;
            const short* Bb = (const short*)B1p + (ntile * 4 * 64 + lane) * 8;
#pragma unroll
            for (int ks = 0; ks < 4; ++ks) {
                short8 bf = *(const short8*)(Bb + ks * 512);
                acc[nt] = __builtin_amdgcn_mfma_f32_16x16x32_bf16(af[ks], bf, acc[nt], 0, 0, 0);
            }
        }
#pragma unroll
        for (int nt = 0; nt < 4; ++nt) {
            int col = w * 64 + nt * 16 + l16;
            float bias = b1[col];
#pragma unroll
            for (int r = 0; r < 4; ++r)
                Ht[(quad * 4 + r) * 520 + col] = f2bf(fmaxf(acc[nt][r] + bias, 0.f));
        }
    }
    __syncthreads();

    // ---- phase C: waves 0-3 -> Pb cols wh*32..+31; waves 4-7 -> Q same ----
    int isQ = w >> 2;
    int wh = w & 3;
    int tbase = isQ * 8 + wh * 2;                     // B2p 16-col tile base
    floatx4 acc0 = {0.f, 0.f, 0.f, 0.f};
    floatx4 acc1 = {0.f, 0.f, 0.f, 0.f};
    const short* Bc0 = (const short*)B2p + ((tbase * 16) * 64 + lane) * 8;
    const short* Bc1 = (const short*)B2p + (((tbase + 1) * 16) * 64 + lane) * 8;
#pragma unroll 4
    for (int ks = 0; ks < 16; ++ks) {
        short8 a2 = *(const short8*)&Ht[l16 * 520 + ks * 32 + quad * 8];
        short8 bf0 = *(const short8*)(Bc0 + ks * 512);
        short8 bf1 = *(const short8*)(Bc1 + ks * 512);
        acc0 = __builtin_amdgcn_mfma_f32_16x16x32_bf16(a2, bf0, acc0, 0, 0, 0);
        acc1 = __builtin_amdgcn_mfma_f32_16x16x32_bf16(a2, bf1, acc1, 0, 0, 0);
    }
    if (!isQ) {
#pragma unroll
        for (int r = 0; r < 4; ++r) {
            int row = m0 + quad * 4 + r;
            Pb[row * 128 + wh * 32 + l16]      = __float2bfloat16(acc0[r]);
            Pb[row * 128 + wh * 32 + 16 + l16] = __float2bfloat16(acc1[r]);
        }
    } else {
#pragma unroll
        for (int r = 0; r < 4; ++r) {
            int row = m0 + quad * 4 + r;
            Q[row * 128 + wh * 32 + l16]      = acc0[r];
            Q[row * 128 + wh * 32 + 16 + l16] = acc1[r];
        }
    }
}

// ---------------- final: out = mean_agg(Pb)[:, :121] + Q[:, :121] + b2; one wave per node ----------------

__global__ __launch_bounds__(256) void k_final(const __hip_bfloat16* __restrict__ Pb,
                                               const float* __restrict__ Q, const float* __restrict__ b2,
                                               const int* __restrict__ cursor, const int* __restrict__ csr,
                                               float* __restrict__ out) {
    int lane = threadIdx.x & 63;
    int nu = __builtin_amdgcn_readfirstlane(blockIdx.x * 4 + (threadIdx.x >> 6));
    int dt = cursor[nu];
    int d = min(dt, DMAX);
    const int* crow = csr + nu * DMAX;
    const unsigned* Pw = (const unsigned*)Pb;          // 2 bf16 cols per 4B word; lane owns cols 2t, 2t+1
    float lo0 = 0.f, lo1 = 0.f, lo2 = 0.f, lo3 = 0.f;
    float hi0 = 0.f, hi1 = 0.f, hi2 = 0.f, hi3 = 0.f;
    int j = 0;
    for (; j + 8 <= d; j += 8) {                       // ids via one s_load_dwordx8
        int i0 = crow[j], i1 = crow[j + 1], i2 = crow[j + 2], i3 = crow[j + 3];
        int i4 = crow[j + 4], i5 = crow[j + 5], i6 = crow[j + 6], i7 = crow[j + 7];
        unsigned w0 = Pw[i0 * 64 + lane];
        unsigned w1 = Pw[i1 * 64 + lane];
        unsigned w2 = Pw[i2 * 64 + lane];
        unsigned w3 = Pw[i3 * 64 + lane];
        unsigned w4 = Pw[i4 * 64 + lane];
        unsigned w5 = Pw[i5 * 64 + lane];
        unsigned w6 = Pw[i6 * 64 + lane];
        unsigned w7 = Pw[i7 * 64 + lane];
        lo0 += __uint_as_float(w0 << 16); hi0 += __uint_as_float(w0 & 0xffff0000u);
        lo1 += __uint_as_float(w1 << 16); hi1 += __uint_as_float(w1 & 0xffff0000u);
        lo2 += __uint_as_float(w2 << 16); hi2 += __uint_as_float(w2 & 0xffff0000u);
        lo3 += __uint_as_float(w3 << 16); hi3 += __uint_as_float(w3 & 0xffff0000u);
        lo0 += __uint_as_float(w4 << 16); hi0 += __uint_as_float(w4 & 0xffff0000u);
        lo1 += __uint_as_float(w5 << 16); hi1 += __uint_as_float(w5 & 0xffff0000u);
        lo2 += __uint_as_float(w6 << 16); hi2 += __uint_as_float(w6 & 0xffff0000u);
        lo3 += __uint_as_float(w7 << 16); hi3 += __uint_as_float(w7 & 0xffff0000u);
    }
    for (; j < d; ++j) {
        int i0 = crow[j];
        unsigned w0 = Pw[i0 * 64 + lane];
        lo0 += __uint_as_float(w0 << 16); hi0 += __uint_as_float(w0 & 0xffff0000u);
    }
    float slo = (lo0 + lo1) + (lo2 + lo3);
    float shi = (hi0 + hi1) + (hi2 + hi3);
    float invd = (dt > 0) ? 1.f / (float)dt : 1.f;
    int c0 = lane * 2, c1 = lane * 2 + 1;
    if (c0 < OUTF) out[nu * OUTF + c0] = slo * invd + Q[nu * 128 + c0] + b2[c0];
    if (c1 < OUTF) out[nu * OUTF + c1] = shi * invd + Q[nu * 128 + c1] + b2[c1];
}

extern "C" void kernel_launch(void* const* d_in, const int* in_sizes, int n_in,
                              void* d_out, int out_size, void* d_ws, size_t ws_size,
                              hipStream_t stream) {
    const float* x   = (const float*)d_in[0];
    const int* edges = (const int*)d_in[1];
    const float* W1l = (const float*)d_in[2];
    const float* W1r = (const float*)d_in[3];
    const float* b1  = (const float*)d_in[4];
    const float* W2l = (const float*)d_in[5];
    const float* W2r = (const float*)d_in[6];
    const float* b2  = (const float*)d_in[7];
    float* out = (float*)d_out;

    char* ws = (char*)d_ws;
    int* cursor         = (int*)(ws + 0);                    // 40,000 B
    int* csr            = (int*)(ws + 40000);                // 2,560,000 B [NN,64]
    __hip_bfloat16* xp  = (__hip_bfloat16*)(ws + 2600000);   // 1,280,000 B [NN,64]
    __hip_bfloat16* Pb  = (__hip_bfloat16*)(ws + 3880000);   // 2,560,000 B [NN,128]
    float* Q            = (float*)(ws + 6440000);            // 5,120,000 B [NN,128]
    __hip_bfloat16* B1p = (__hip_bfloat16*)(ws + 11560000);  // 131,072 B
    __hip_bfloat16* B2p = (__hip_bfloat16*)(ws + 11691072);  // 262,144 B

    const int* srcv = edges;
    const int* dstv = edges + NE;

    k_prep<<<512, 256, 0, stream>>>(x, W1l, W1r, W2l, W2r, cursor, xp, B1p, B2p);
    k_fill<<<625, 256, 0, stream>>>(srcv, dstv, cursor, csr);
    k_fused<<<625, 512, 0, stream>>>(xp, cursor, csr, B1p, b1, B2p, Pb, Q);
    k_final<<<2500, 256, 0, stream>>>(Pb, Q, b2, cursor, csr, out);
}

// Round 8
// 114.406 us; speedup vs baseline: 4.4453x; 1.0091x over previous
//
#include <hip/hip_runtime.h>
#include <hip/hip_bf16.h>

constexpr int NN   = 10000;   // nodes
constexpr int INF  = 50;      // in feats
constexpr int HID  = 512;     // hidden
constexpr int OUTF = 121;     // out feats
constexpr int NE   = 160000;  // edges
constexpr int DMAX = 64;      // per-node neighbor capacity (Poisson(16): P(deg>64) ~ 1e-19)

typedef __attribute__((ext_vector_type(8))) short short8;
typedef __attribute__((ext_vector_type(4))) float floatx4;

__device__ inline float bf2f(unsigned short u) {
    union { unsigned int i; float f; } v; v.i = ((unsigned)u) << 16; return v.f;
}
__device__ inline unsigned short f2bf(float f) {
    __hip_bfloat16 h = __float2bfloat16(f);
    return *(unsigned short*)&h;
}

// ---------------- prep: zero cursor + pack weights (MFMA B-frag order) + pack xp ----------------
// B-frag for 16x16x32: lane L holds B[k = kt*32 + (L>>4)*8 + j][n = nt*16 + (L&15)], j=0..7.
// Bp[((nt*KT + kt)*64 + L)*8 + j]: each lane's 8 elems contiguous (16B), wave coalesced.

__global__ __launch_bounds__(256) void k_prep(const float* __restrict__ x,
                                              const float* __restrict__ W1l, const float* __restrict__ W1r,
                                              const float* __restrict__ W2l, const float* __restrict__ W2r,
                                              int* __restrict__ cursor, __hip_bfloat16* __restrict__ xp,
                                              __hip_bfloat16* __restrict__ B1p, __hip_bfloat16* __restrict__ B2p) {
    int idx = blockIdx.x * 256 + threadIdx.x;
    if (idx < NN) cursor[idx] = 0;
    if (idx < 65536) {  // B1p: W1cat[128x512] = vstack(W1l[50], W1r[50], 0[28]); KT=4, NT=32
        int j = idx & 7, L = (idx >> 3) & 63, kt = (idx >> 9) & 3, nt = idx >> 11;
        int k = kt * 32 + ((L >> 4) * 8 + j);
        int n = nt * 16 + (L & 15);
        float v = (k < 50) ? W1l[k * HID + n] : ((k < 100) ? W1r[(k - 50) * HID + n] : 0.f);
        B1p[idx] = __float2bfloat16(v);
    }
    {   // B2p: W2cat[512x256] = [pad128(W2l) | pad128(W2r)]; KT=16, NT=16
        int j = idx & 7, L = (idx >> 3) & 63, kt = (idx >> 9) & 15, nt = idx >> 13;
        int k = kt * 32 + ((L >> 4) * 8 + j);
        int n = nt * 16 + (L & 15);
        float v;
        if (n < 128) v = (n < OUTF) ? W2l[k * OUTF + n] : 0.f;
        else { int c = n - 128; v = (c < OUTF) ? W2r[k * OUTF + c] : 0.f; }
        B2p[idx] = __float2bfloat16(v);
    }
    // xp[NN][64] bf16: one-cache-line gather rows (cols >= 50 zero)
    for (int r = idx; r < NN * 64; r += 131072) {
        int n = r >> 6, c = r & 63;
        xp[r] = __float2bfloat16(c < INF ? x[n * INF + c] : 0.f);
    }
}

// ---------------- fixed-capacity CSR fill ----------------

__global__ __launch_bounds__(256) void k_fill(const int* __restrict__ srcv, const int* __restrict__ dstv,
                                              int* __restrict__ cursor, int* __restrict__ csr) {
    int e = blockIdx.x * 256 + threadIdx.x;
    if (e < NE) {
        int d = dstv[e];
        if ((unsigned)d < (unsigned)NN) {
            int pos = atomicAdd(&cursor[d], 1);
            int s = srcv[e];
            s = min(max(s, 0), NN - 1);               // guard: csr always holds valid node ids
            if (pos < DMAX) csr[d * DMAX + pos] = s;
        }
    }
}

// ---------------- fused agg1 + GEMM1 + GEMM2: 16 nodes per block, 16 waves (1024 thr) ----------------
// Phase A: ONE node per wave; ids via s_load_dwordx8; gather xp rows (1 cacheline each)
// Phase B: h_tile = relu(As @ W1cat + b1) -> Ht[16][520]; wave w -> cols w*32..+31 (8 MFMA)
// Phase C: waves 0-7 -> Pb (bf16) 16 cols each; waves 8-15 -> Q (fp32) 16 cols each (16 MFMA)

__global__ __launch_bounds__(1024, 4) void k_fused(const __hip_bfloat16* __restrict__ xp,
                                                   const int* __restrict__ cursor, const int* __restrict__ csr,
                                                   const __hip_bfloat16* __restrict__ B1p,
                                                   const float* __restrict__ b1,
                                                   const __hip_bfloat16* __restrict__ B2p,
                                                   __hip_bfloat16* __restrict__ Pb, float* __restrict__ Q) {
    __shared__ __align__(16) unsigned short As[16 * 136];
    __shared__ __align__(16) unsigned short Ht[16 * 520];
    int t = threadIdx.x;
    int w = t >> 6, lane = t & 63, quad = lane >> 4, l16 = lane & 15;
    int m0 = blockIdx.x * 16;
    const unsigned short* xs = (const unsigned short*)xp;

    // ---- phase A: wave w handles node m0 + w ----
    {
        int nu = __builtin_amdgcn_readfirstlane(m0 + w);   // SGPR node id -> s_load path
        int dt = cursor[nu];
        int d = min(dt, DMAX);
        const int* crow = csr + nu * DMAX;
        float s0 = 0.f, s1 = 0.f, s2 = 0.f, s3 = 0.f;
        int j = 0;
        for (; j + 8 <= d; j += 8) {                  // ids arrive as one s_load_dwordx8
            int i0 = crow[j], i1 = crow[j + 1], i2 = crow[j + 2], i3 = crow[j + 3];
            int i4 = crow[j + 4], i5 = crow[j + 5], i6 = crow[j + 6], i7 = crow[j + 7];
            s0 += bf2f(xs[i0 * 64 + lane]);
            s1 += bf2f(xs[i1 * 64 + lane]);
            s2 += bf2f(xs[i2 * 64 + lane]);
            s3 += bf2f(xs[i3 * 64 + lane]);
            s0 += bf2f(xs[i4 * 64 + lane]);
            s1 += bf2f(xs[i5 * 64 + lane]);
            s2 += bf2f(xs[i6 * 64 + lane]);
            s3 += bf2f(xs[i7 * 64 + lane]);
        }
        for (; j < d; ++j) {
            int i0 = crow[j];
            s0 += bf2f(xs[i0 * 64 + lane]);
        }
        float s = (s0 + s1) + (s2 + s3);
        float invd = (dt > 0) ? 1.f / (float)dt : 1.f;
        unsigned short self = xs[nu * 64 + lane];
        if (lane < INF) As[w * 136 + lane] = f2bf(s * invd);
        As[w * 136 + 50 + lane] = self;               // cols 50..113 (100..113 zeros from xp pad)
        if (lane < 7) *(unsigned*)&As[w * 136 + 114 + 2 * lane] = 0u;  // cols 114..127
    }
    __syncthreads();

    // ---- phase B: wave w covers cols w*32 .. +31 of h ----
    short8 af[4];
#pragma unroll
    for (int ks = 0; ks < 4; ++ks) af[ks] = *(const short8*)&As[l16 * 136 + ks * 32 + quad * 8];
    {
        floatx4 acc[2];
#pragma unroll
        for (int nt = 0; nt < 2; ++nt) acc[nt] = floatx4{0.f, 0.f, 0.f, 0.f};
#pragma unroll
        for (int nt = 0; nt < 2; ++nt) {
            int ntile = w * 2 + nt;
            const short* Bb = (const short*)B1p + (ntile * 4 * 64 + lane) * 8;
#pragma unroll
            for (int ks = 0; ks < 4; ++ks) {
                short8 bf = *(const short8*)(Bb + ks * 512);
                acc[nt] = __builtin_amdgcn_mfma_f32_16x16x32_bf16(af[ks], bf, acc[nt], 0, 0, 0);
            }
        }
#pragma unroll
        for (int nt = 0; nt < 2; ++nt) {
            int col = w * 32 + nt * 16 + l16;
            float bias = b1[col];
#pragma unroll
            for (int r = 0; r < 4; ++r)
                Ht[(quad * 4 + r) * 520 + col] = f2bf(fmaxf(acc[nt][r] + bias, 0.f));
        }
    }
    __syncthreads();

    // ---- phase C: waves 0-7 -> Pb cols wh*16..+15; waves 8-15 -> Q same ----
    int isQ = w >> 3;
    int wh = w & 7;
    int ntile2 = isQ * 8 + wh;                        // B2p 16-col tile index
    floatx4 acc = {0.f, 0.f, 0.f, 0.f};
    const short* Bc = (const short*)B2p + ((ntile2 * 16) * 64 + lane) * 8;
#pragma unroll 4
    for (int ks = 0; ks < 16; ++ks) {
        short8 a2 = *(const short8*)&Ht[l16 * 520 + ks * 32 + quad * 8];
        short8 bf = *(const short8*)(Bc + ks * 512);
        acc = __builtin_amdgcn_mfma_f32_16x16x32_bf16(a2, bf, acc, 0, 0, 0);
    }
    if (!isQ) {
#pragma unroll
        for (int r = 0; r < 4; ++r) {
            int row = m0 + quad * 4 + r;
            Pb[row * 128 + wh * 16 + l16] = __float2bfloat16(acc[r]);
        }
    } else {
#pragma unroll
        for (int r = 0; r < 4; ++r) {
            int row = m0 + quad * 4 + r;
            Q[row * 128 + wh * 16 + l16] = acc[r];
        }
    }
}

// ---------------- final: out = mean_agg(Pb)[:, :121] + Q[:, :121] + b2; one wave per node ----------------

__global__ __launch_bounds__(256) void k_final(const __hip_bfloat16* __restrict__ Pb,
                                               const float* __restrict__ Q, const float* __restrict__ b2,
                                               const int* __restrict__ cursor, const int* __restrict__ csr,
                                               float* __restrict__ out) {
    int lane = threadIdx.x & 63;
    int nu = __builtin_amdgcn_readfirstlane(blockIdx.x * 4 + (threadIdx.x >> 6));
    int dt = cursor[nu];
    int d = min(dt, DMAX);
    const int* crow = csr + nu * DMAX;
    const unsigned* Pw = (const unsigned*)Pb;          // 2 bf16 cols per 4B word; lane owns cols 2t, 2t+1
    float lo0 = 0.f, lo1 = 0.f, lo2 = 0.f, lo3 = 0.f;
    float hi0 = 0.f, hi1 = 0.f, hi2 = 0.f, hi3 = 0.f;
    int j = 0;
    for (; j + 8 <= d; j += 8) {                       // ids via one s_load_dwordx8
        int i0 = crow[j], i1 = crow[j + 1], i2 = crow[j + 2], i3 = crow[j + 3];
        int i4 = crow[j + 4], i5 = crow[j + 5], i6 = crow[j + 6], i7 = crow[j + 7];
        unsigned w0 = Pw[i0 * 64 + lane];
        unsigned w1 = Pw[i1 * 64 + lane];
        unsigned w2 = Pw[i2 * 64 + lane];
        unsigned w3 = Pw[i3 * 64 + lane];
        unsigned w4 = Pw[i4 * 64 + lane];
        unsigned w5 = Pw[i5 * 64 + lane];
        unsigned w6 = Pw[i6 * 64 + lane];
        unsigned w7 = Pw[i7 * 64 + lane];
        lo0 += __uint_as_float(w0 << 16); hi0 += __uint_as_float(w0 & 0xffff0000u);
        lo1 += __uint_as_float(w1 << 16); hi1 += __uint_as_float(w1 & 0xffff0000u);
        lo2 += __uint_as_float(w2 << 16); hi2 += __uint_as_float(w2 & 0xffff0000u);
        lo3 += __uint_as_float(w3 << 16); hi3 += __uint_as_float(w3 & 0xffff0000u);
        lo0 += __uint_as_float(w4 << 16); hi0 += __uint_as_float(w4 & 0xffff0000u);
        lo1 += __uint_as_float(w5 << 16); hi1 += __uint_as_float(w5 & 0xffff0000u);
        lo2 += __uint_as_float(w6 << 16); hi2 += __uint_as_float(w6 & 0xffff0000u);
        lo3 += __uint_as_float(w7 << 16); hi3 += __uint_as_float(w7 & 0xffff0000u);
    }
    for (; j < d; ++j) {
        int i0 = crow[j];
        unsigned w0 = Pw[i0 * 64 + lane];
        lo0 += __uint_as_float(w0 << 16); hi0 += __uint_as_float(w0 & 0xffff0000u);
    }
    float slo = (lo0 + lo1) + (lo2 + lo3);
    float shi = (hi0 + hi1) + (hi2 + hi3);
    float invd = (dt > 0) ? 1.f / (float)dt : 1.f;
    int c0 = lane * 2, c1 = lane * 2 + 1;
    if (c0 < OUTF) out[nu * OUTF + c0] = slo * invd + Q[nu * 128 + c0] + b2[c0];
    if (c1 < OUTF) out[nu * OUTF + c1] = shi * invd + Q[nu * 128 + c1] + b2[c1];
}

extern "C" void kernel_launch(void* const* d_in, const int* in_sizes, int n_in,
                              void* d_out, int out_size, void* d_ws, size_t ws_size,
                              hipStream_t stream) {
    const float* x   = (const float*)d_in[0];
    const int* edges = (const int*)d_in[1];
    const float* W1l = (const float*)d_in[2];
    const float* W1r = (const float*)d_in[3];
    const float* b1  = (const float*)d_in[4];
    const float* W2l = (const float*)d_in[5];
    const float* W2r = (const float*)d_in[6];
    const float* b2  = (const float*)d_in[7];
    float* out = (float*)d_out;

    char* ws = (char*)d_ws;
    int* cursor         = (int*)(ws + 0);                    // 40,000 B
    int* csr            = (int*)(ws + 40000);                // 2,560,000 B [NN,64]
    __hip_bfloat16* xp  = (__hip_bfloat16*)(ws + 2600000);   // 1,280,000 B [NN,64]
    __hip_bfloat16* Pb  = (__hip_bfloat16*)(ws + 3880000);   // 2,560,000 B [NN,128]
    float* Q            = (float*)(ws + 6440000);            // 5,120,000 B [NN,128]
    __hip_bfloat16* B1p = (__hip_bfloat16*)(ws + 11560000);  // 131,072 B
    __hip_bfloat16* B2p = (__hip_bfloat16*)(ws + 11691072);  // 262,144 B

    const int* srcv = edges;
    const int* dstv = edges + NE;

    k_prep<<<512, 256, 0, stream>>>(x, W1l, W1r, W2l, W2r, cursor, xp, B1p, B2p);
    k_fill<<<625, 256, 0, stream>>>(srcv, dstv, cursor, csr);
    k_fused<<<625, 1024, 0, stream>>>(xp, cursor, csr, B1p, b1, B2p, Pb, Q);
    k_final<<<2500, 256, 0, stream>>>(Pb, Q, b2, cursor, csr, out);
}